// Round 13
// baseline (319.249 us; speedup 1.0000x reference)
//
#include <hip/hip_runtime.h>
#include <math.h>

// Capsule dynamic routing, fused-recompute. fp32.
// B=512, R=1152, C=10, O=16, I=8.
//   iter0: c_ij = 1/10 uniform  -> s0 = 0.1 * sum_r u_hat
//   iter2: b2 = u.(v0+v1)       -> only running vsum kept
// R12 post-mortem: nontemporal 16B stores defeated write-combining
// (WRITE 31->67MB, partial-line HBM transactions) and pushed partials
// out of L2 (reduce re-reads at HBM latency). FETCH was already ideal
// (25.8MB = W + xt) -> the L2-eviction fear was unfounded at RT=96.
// R13: clean A/B of the R11 occupancy plan: RT=96 -> grid 768 = exactly
// 3 blocks/CU, CHUNK=4 double-buffer = 40KB LDS, REGULAR stores/loads,
// inner r-loop fully unrolled. Everything else identical to R12.

#define R_TOT 1152
#define C_N 10
#define O_N 16
#define I_N 8
#define B_TOT 512
#define RT 96                                   // rtile count (partial slices)
#define RCHB 12                                 // r's per block
#define CHUNK 4                                 // r's per staged chunk
#define NCH 3                                   // chunks per block
#define SEG (B_TOT * C_N * O_N)                 // 81920 floats per partial slice
#define WSLAB (C_N * O_N * I_N)                 // 1280 floats per r
#define GRAN (WSLAB / 4)                        // 320 float4 granules per r
#define CG (CHUNK * GRAN)                       // 1280 granules per chunk

// granule swizzle within a slab: XOR bits[2:0] with bits[5:3] (involution).
__device__ __forceinline__ int swz(int g) { return g ^ ((g >> 3) & 7); }

// quad_perm DPP cross-lane adds (VALU pipe, not LDS): xor1 / xor2 over oq.
__device__ __forceinline__ float quad_add1(float v) {
  return v + __int_as_float(__builtin_amdgcn_update_dpp(
      0, __float_as_int(v), 0xB1 /*[1,0,3,2]*/, 0xF, 0xF, true));
}
__device__ __forceinline__ float quad_add2(float v) {
  return v + __int_as_float(__builtin_amdgcn_update_dpp(
      0, __float_as_int(v), 0x4E /*[2,3,0,1]*/, 0xF, 0xF, true));
}

// x[b][r][i] -> x_t[r][b][i]
__global__ __launch_bounds__(256) void transpose_x(
    const float* __restrict__ x, float* __restrict__ xt)
{
  const int t = blockIdx.x * 256 + threadIdx.x;   // t = b*R_TOT + r
  const int b = t / R_TOT;
  const int r = t - b * R_TOT;
  const float4* src = reinterpret_cast<const float4*>(x) + (size_t)t * 2;
  float4* dst = reinterpret_cast<float4*>(xt) + ((size_t)r * B_TOT + b) * 2;
  dst[0] = src[0];
  dst[1] = src[1];
}

// one r-step: u = W.x for this thread's (5c x 4o x 2b), then routing update.
template<bool UNIFORM>
__device__ __forceinline__ void body(
    const float4* const (&A)[8], int slab,     // granule offset (compile-time)
    const float (&xc)[2][8],
    const float (&vf)[5][2][4],
    float (&sacc)[5][2][4])
{
  float u[5][2][4];
  #pragma unroll
  for (int cc = 0; cc < 5; ++cc) {
    #pragma unroll
    for (int jo = 0; jo < 4; ++jo) {
      const float4 w0 = A[(2 * jo)     ^ ((cc & 1) << 2)][slab + cc * 32];
      const float4 w1 = A[(2 * jo + 1) ^ ((cc & 1) << 2)][slab + cc * 32];
      #pragma unroll
      for (int k = 0; k < 2; ++k) {
        u[cc][k][jo] =
            w0.x * xc[k][0] + w0.y * xc[k][1] + w0.z * xc[k][2] + w0.w * xc[k][3]
          + w1.x * xc[k][4] + w1.y * xc[k][5] + w1.z * xc[k][6] + w1.w * xc[k][7];
      }
    }
  }

  if constexpr (UNIFORM) {
    #pragma unroll
    for (int cc = 0; cc < 5; ++cc)
      #pragma unroll
      for (int k = 0; k < 2; ++k)
        #pragma unroll
        for (int jo = 0; jo < 4; ++jo)
          sacc[cc][k][jo] += u[cc][k][jo];
  } else {
    float bij[5][2];
    #pragma unroll
    for (int cc = 0; cc < 5; ++cc) {
      #pragma unroll
      for (int k = 0; k < 2; ++k) {
        float a = u[cc][k][0] * vf[cc][k][0] + u[cc][k][1] * vf[cc][k][1]
                + u[cc][k][2] * vf[cc][k][2] + u[cc][k][3] * vf[cc][k][3];
        a = quad_add1(a);        // + lane^1  (oq)
        a = quad_add2(a);        // + lane^2  (oq)
        bij[cc][k] = a;
      }
    }
    #pragma unroll
    for (int k = 0; k < 2; ++k) {
      float m = bij[0][k];
      #pragma unroll
      for (int cc = 1; cc < 5; ++cc) m = fmaxf(m, bij[cc][k]);
      m = fmaxf(m, __shfl_xor(m, 4));
      float e[5];
      float den = 0.0f;
      #pragma unroll
      for (int cc = 0; cc < 5; ++cc) { e[cc] = __expf(bij[cc][k] - m); den += e[cc]; }
      den += __shfl_xor(den, 4);
      const float inv = __builtin_amdgcn_rcpf(den);
      #pragma unroll
      for (int cc = 0; cc < 5; ++cc) {
        const float cw = e[cc] * inv;
        #pragma unroll
        for (int jo = 0; jo < 4; ++jo)
          sacc[cc][k][jo] += cw * u[cc][k][jo];
      }
    }
  }
}

// lane map: oq = lane&3, ch = (lane>>2)&1, bl = lane>>3; thread owns
// b0 = btile*64 + wave*16 + bl*2 (+k), c = ch*5+cc, o = oq*4+jo.
// grid 768: xcd = bid&7, idx = bid>>3 (0..95); rtile = xcd*12 + idx%12,
// btile = idx/12. Each XCD owns 12 contiguous rtiles (720KB W + 2.4MB xt
// working set, L2-resident).
template<bool UNIFORM>
__global__ __launch_bounds__(256, 2) void acc_kernel(
    const float* __restrict__ xt, const float* __restrict__ W,
    const float* __restrict__ vsum, float* __restrict__ part)
{
  __shared__ float4 wbuf[2 * CG];   // 40 KB: two 4-slab chunks

  const int tid  = threadIdx.x;
  const int wave = tid >> 6;
  const int lane = tid & 63;
  const int oq   = lane & 3;
  const int ch   = (lane >> 2) & 1;
  const int bl   = lane >> 3;

  const int bid   = blockIdx.x;
  const int xcd   = bid & 7;
  const int idx   = bid >> 3;             // 0..95
  const int rtile = xcd * 12 + (idx % 12);
  const int btile = idx / 12;             // 0..7

  const int b0 = btile * 64 + wave * 16 + bl * 2;
  const int r0 = rtile * RCHB;

  auto stage = [&](int ci, int buf) {
    const float4* wc = reinterpret_cast<const float4*>(W)
                     + (size_t)(r0 + ci * CHUNK) * GRAN;
    float4* dst = &wbuf[buf * CG];
    #pragma unroll
    for (int s = 0; s < CHUNK; ++s) {
      dst[s * GRAN + swz(tid)] = wc[s * GRAN + tid];
      if (tid < GRAN - 256)
        dst[s * GRAN + swz(tid + 256)] = wc[s * GRAN + tid + 256];
    }
  };

  auto xload = [&](int r, float (&dst)[2][8]) {
    const float4* xp = reinterpret_cast<const float4*>(xt) + ((size_t)r * B_TOT + b0) * 2;
    #pragma unroll
    for (int k = 0; k < 2; ++k) {
      const float4 a = xp[2 * k], b = xp[2 * k + 1];
      dst[k][0] = a.x; dst[k][1] = a.y; dst[k][2] = a.z; dst[k][3] = a.w;
      dst[k][4] = b.x; dst[k][5] = b.y; dst[k][6] = b.z; dst[k][7] = b.w;
    }
  };

  // 8 swizzled LDS base pointers (granule units): ch*160 + oq*8 + (j ^ xv)
  const int xv = (ch << 2) | oq;
  const float4* A[8];
  #pragma unroll
  for (int j = 0; j < 8; ++j)
    A[j] = &wbuf[ch * 160 + oq * 8 + (j ^ xv)];

  float vf[5][2][4];
  if constexpr (!UNIFORM) {
    #pragma unroll
    for (int cc = 0; cc < 5; ++cc)
      #pragma unroll
      for (int k = 0; k < 2; ++k) {
        const float4 tv = *reinterpret_cast<const float4*>(
            &vsum[((b0 + k) * C_N + ch * 5 + cc) * O_N + oq * 4]);
        vf[cc][k][0] = tv.x; vf[cc][k][1] = tv.y; vf[cc][k][2] = tv.z; vf[cc][k][3] = tv.w;
      }
  }

  float sacc[5][2][4];
  #pragma unroll
  for (int cc = 0; cc < 5; ++cc)
    #pragma unroll
    for (int k = 0; k < 2; ++k)
      #pragma unroll
      for (int jo = 0; jo < 4; ++jo) sacc[cc][k][jo] = 0.0f;

  float xc[2][8], xn[2][8];
  stage(0, 0);
  xload(r0, xc);
  __syncthreads();

  #pragma unroll 1
  for (int ci = 0; ci < NCH; ++ci) {
    if (ci + 1 < NCH) stage(ci + 1, (ci + 1) & 1);
    const int sb = (ci & 1) * CG;
    #pragma unroll
    for (int rr = 0; rr < CHUNK; ++rr) {
      const int rl = ci * CHUNK + rr;
      const int rn = (rl + 1 < RCHB) ? rl + 1 : rl;
      xload(r0 + rn, xn);                 // prefetch next x under compute
      body<UNIFORM>(A, sb + rr * GRAN, xc, vf, sacc);
      #pragma unroll
      for (int k = 0; k < 2; ++k)
        #pragma unroll
        for (int i = 0; i < 8; ++i) xc[k][i] = xn[k][i];
    }
    __syncthreads();
  }

  const float scale = UNIFORM ? 0.1f : 1.0f;
  float* pb = part + (size_t)rtile * SEG;
  #pragma unroll
  for (int cc = 0; cc < 5; ++cc)
    #pragma unroll
    for (int k = 0; k < 2; ++k) {
      float4 v;
      v.x = sacc[cc][k][0] * scale; v.y = sacc[cc][k][1] * scale;
      v.z = sacc[cc][k][2] * scale; v.w = sacc[cc][k][3] * scale;
      *reinterpret_cast<float4*>(
          &pb[((b0 + k) * C_N + ch * 5 + cc) * O_N + oq * 4]) = v;
    }
}

// reduce over rtiles + squash over O=16 per (b,c). grid = SEG/64 blocks.
// MODE 0: vsum = v ; MODE 1: vsum += v ; MODE 2: out = v
template<int MODE>
__global__ __launch_bounds__(256) void reduce_squash(
    const float* __restrict__ part, int nrt,
    float* __restrict__ vsum, float* __restrict__ out)
{
  __shared__ float lds[4][64];
  const int tid = threadIdx.x;
  const int l   = tid & 63;
  const int q   = tid >> 6;
  const int j   = blockIdx.x * 64 + l;
  const float* p = part + j;
  float sv = 0.0f;
  #pragma unroll 4
  for (int rt = q; rt < nrt; rt += 4) sv += p[(size_t)rt * SEG];
  lds[q][l] = sv;
  __syncthreads();
  if (q == 0) {
    sv = lds[0][l] + lds[1][l] + lds[2][l] + lds[3][l];
    float sq = sv * sv;
    sq += __shfl_xor(sq, 1);
    sq += __shfl_xor(sq, 2);
    sq += __shfl_xor(sq, 4);
    sq += __shfl_xor(sq, 8);
    const float scale = sq / (1.0f + sq) * rsqrtf(sq + 1e-8f);
    const float v = scale * sv;
    if constexpr (MODE == 0)      vsum[j] = v;
    else if constexpr (MODE == 1) vsum[j] += v;
    else                          out[j] = v;
  }
}

extern "C" void kernel_launch(void* const* d_in, const int* in_sizes, int n_in,
                              void* d_out, int out_size, void* d_ws, size_t ws_size,
                              hipStream_t stream) {
  (void)in_sizes; (void)n_in; (void)out_size; (void)ws_size;
  const float* x = (const float*)d_in[0];
  const float* W = (const float*)d_in[1];
  float* out  = (float*)d_out;   // doubles as vsum; fully rewritten with v2
  float* part = (float*)d_ws;    // RT * SEG floats = 31.4 MB
  float* xt   = part + (size_t)RT * SEG;   // 18.9 MB (50.3 MB total, proven fit R6)

  const dim3 blk(256), accGrid(8 * RT), sqGrid(SEG / 64);

  hipLaunchKernelGGL(transpose_x, dim3((B_TOT * R_TOT) / 256), blk, 0, stream, x, xt);

  // iter 0: uniform coefficients (softmax of zeros)
  hipLaunchKernelGGL((acc_kernel<true>),  accGrid, blk, 0, stream, xt, W, out, part);
  hipLaunchKernelGGL((reduce_squash<0>),  sqGrid,  blk, 0, stream, part, RT, out, out);  // vsum = v0
  // iter 1
  hipLaunchKernelGGL((acc_kernel<false>), accGrid, blk, 0, stream, xt, W, out, part);
  hipLaunchKernelGGL((reduce_squash<1>),  sqGrid,  blk, 0, stream, part, RT, out, out);  // vsum = v0+v1
  // iter 2
  hipLaunchKernelGGL((acc_kernel<false>), accGrid, blk, 0, stream, xt, W, out, part);
  hipLaunchKernelGGL((reduce_squash<2>),  sqGrid,  blk, 0, stream, part, RT, out, out);  // out = v2
}

// Round 14
// 311.906 us; speedup vs baseline: 1.0235x; 1.0235x over previous
//
#include <hip/hip_runtime.h>
#include <math.h>

// Capsule dynamic routing, fused-recompute. fp32.
// B=512, R=1152, C=10, O=16, I=8.
//   iter0: c_ij = 1/10 uniform  -> s0 = 0.1 * sum_r u_hat
//   iter2: b2 = u.(v0+v1)       -> only running vsum kept
// R13 post-mortem: full-unroll spilled (FETCH 96MB/WRITE 157MB scratch);
// A/B was confounded. Discipline: R7 (161us, acc 65us, no spill) is the
// only stable base; ONE change per round.
// R14 = R7 verbatim + ONE change: split W reads across pipes. Each
// (cc,jo) FMA needs granules w0 (i<4) and w1 (i>=4). w0 comes from LDS
// (as before); w1 comes DIRECTLY from global W (8 distinct addrs/wave
// -> ~2 cache lines, L1/L2-hit; W is XCD-resident; VMEM pipe idle).
// LDS reads/thread-iter: 40 -> 20 (per-CU LDS floor 29 -> ~15us).
// Staging, swizzle, loop, stores, grid: R7 unchanged.

#define R_TOT 1152
#define C_N 10
#define O_N 16
#define I_N 8
#define B_TOT 512
#define RT 64                                   // rtile count (partial slices)
#define RCHB 18                                 // r's per block
#define CHUNK 6                                 // r's per staged chunk
#define NCH 3                                   // chunks per block
#define SEG (B_TOT * C_N * O_N)                 // 81920 floats per partial slice
#define XT_FLOATS ((size_t)B_TOT * R_TOT * I_N) // 18.9 MB
#define WSLAB (C_N * O_N * I_N)                 // 1280 floats per r
#define GRAN (WSLAB / 4)                        // 320 float4 granules per r
#define CG (CHUNK * GRAN)                       // 1920 granules per chunk

// granule swizzle within a slab: XOR bits[2:0] with bits[5:3] (involution).
__device__ __forceinline__ int swz(int g) { return g ^ ((g >> 3) & 7); }

// quad_perm DPP cross-lane adds (VALU pipe, not LDS): xor1 / xor2 over oq.
__device__ __forceinline__ float quad_add1(float v) {
  return v + __int_as_float(__builtin_amdgcn_update_dpp(
      0, __float_as_int(v), 0xB1 /*[1,0,3,2]*/, 0xF, 0xF, true));
}
__device__ __forceinline__ float quad_add2(float v) {
  return v + __int_as_float(__builtin_amdgcn_update_dpp(
      0, __float_as_int(v), 0x4E /*[2,3,0,1]*/, 0xF, 0xF, true));
}

// x[b][r][i] -> x_t[r][b][i]
__global__ __launch_bounds__(256) void transpose_x(
    const float* __restrict__ x, float* __restrict__ xt)
{
  const int t = blockIdx.x * 256 + threadIdx.x;   // t = b*R_TOT + r
  const int b = t / R_TOT;
  const int r = t - b * R_TOT;
  const float4* src = reinterpret_cast<const float4*>(x) + (size_t)t * 2;
  float4* dst = reinterpret_cast<float4*>(xt) + ((size_t)r * B_TOT + b) * 2;
  dst[0] = src[0];
  dst[1] = src[1];
}

// one r-step: u = W.x for this thread's (5c x 4o x 2b), then routing update.
// w0 (i<4) from swizzled LDS; w1 (i>=4) from global (L1/L2-hit).
template<bool UNIFORM>
__device__ __forceinline__ void body(
    const float4* const (&A)[8], int slab,     // granule offset (runtime)
    const float4* __restrict__ Wg,             // global w1 base for this r
    const float (&xc)[2][8],
    const float (&vf)[5][2][4],
    float (&sacc)[5][2][4])
{
  float u[5][2][4];
  #pragma unroll
  for (int cc = 0; cc < 5; ++cc) {
    #pragma unroll
    for (int jo = 0; jo < 4; ++jo) {
      const float4 w0 = A[(2 * jo) ^ ((cc & 1) << 2)][slab + cc * 32];
      const float4 w1 = Wg[cc * 32 + jo * 2];      // compile-time offset
      #pragma unroll
      for (int k = 0; k < 2; ++k) {
        u[cc][k][jo] =
            w0.x * xc[k][0] + w0.y * xc[k][1] + w0.z * xc[k][2] + w0.w * xc[k][3]
          + w1.x * xc[k][4] + w1.y * xc[k][5] + w1.z * xc[k][6] + w1.w * xc[k][7];
      }
    }
  }

  if constexpr (UNIFORM) {
    #pragma unroll
    for (int cc = 0; cc < 5; ++cc)
      #pragma unroll
      for (int k = 0; k < 2; ++k)
        #pragma unroll
        for (int jo = 0; jo < 4; ++jo)
          sacc[cc][k][jo] += u[cc][k][jo];
  } else {
    float bij[5][2];
    #pragma unroll
    for (int cc = 0; cc < 5; ++cc) {
      #pragma unroll
      for (int k = 0; k < 2; ++k) {
        float a = u[cc][k][0] * vf[cc][k][0] + u[cc][k][1] * vf[cc][k][1]
                + u[cc][k][2] * vf[cc][k][2] + u[cc][k][3] * vf[cc][k][3];
        a = quad_add1(a);        // + lane^1  (oq)
        a = quad_add2(a);        // + lane^2  (oq)
        bij[cc][k] = a;
      }
    }
    #pragma unroll
    for (int k = 0; k < 2; ++k) {
      float m = bij[0][k];
      #pragma unroll
      for (int cc = 1; cc < 5; ++cc) m = fmaxf(m, bij[cc][k]);
      m = fmaxf(m, __shfl_xor(m, 4));
      float e[5];
      float den = 0.0f;
      #pragma unroll
      for (int cc = 0; cc < 5; ++cc) { e[cc] = __expf(bij[cc][k] - m); den += e[cc]; }
      den += __shfl_xor(den, 4);
      const float inv = __builtin_amdgcn_rcpf(den);
      #pragma unroll
      for (int cc = 0; cc < 5; ++cc) {
        const float cw = e[cc] * inv;
        #pragma unroll
        for (int jo = 0; jo < 4; ++jo)
          sacc[cc][k][jo] += cw * u[cc][k][jo];
      }
    }
  }
}

// lane map: oq = lane&3, ch = (lane>>2)&1, bl = lane>>3; thread owns
// b0 = btile*64 + wave*16 + bl*2 (+k), c = ch*5+cc, o = oq*4+jo.
// grid 512 (1D): xcd = bid&7, idx = bid>>3; rtile = xcd*8 + (idx&7),
// btile = idx>>3. Each XCD owns 8 contiguous rtiles.
template<bool UNIFORM>
__global__ __launch_bounds__(256, 2) void acc_kernel(
    const float* __restrict__ xt, const float* __restrict__ W,
    const float* __restrict__ vsum, float* __restrict__ part)
{
  __shared__ float4 wbuf[2 * CG];   // 60 KB: two 6-slab chunks

  const int tid  = threadIdx.x;
  const int wave = tid >> 6;
  const int lane = tid & 63;
  const int oq   = lane & 3;
  const int ch   = (lane >> 2) & 1;
  const int bl   = lane >> 3;

  const int bid   = blockIdx.x;
  const int xcd   = bid & 7;
  const int idx   = bid >> 3;             // 0..63
  const int rtile = xcd * 8 + (idx & 7);
  const int btile = idx >> 3;             // 0..7

  const int b0 = btile * 64 + wave * 16 + bl * 2;
  const int r0 = rtile * RCHB;

  auto stage = [&](int ci, int buf) {
    const float4* wc = reinterpret_cast<const float4*>(W)
                     + (size_t)(r0 + ci * CHUNK) * GRAN;
    float4* dst = &wbuf[buf * CG];
    #pragma unroll
    for (int s = 0; s < CHUNK; ++s) {
      dst[s * GRAN + swz(tid)] = wc[s * GRAN + tid];
      if (tid < GRAN - 256)
        dst[s * GRAN + swz(tid + 256)] = wc[s * GRAN + tid + 256];
    }
  };

  auto xload = [&](int r, float (&dst)[2][8]) {
    const float4* xp = reinterpret_cast<const float4*>(xt) + ((size_t)r * B_TOT + b0) * 2;
    #pragma unroll
    for (int k = 0; k < 2; ++k) {
      const float4 a = xp[2 * k], b = xp[2 * k + 1];
      dst[k][0] = a.x; dst[k][1] = a.y; dst[k][2] = a.z; dst[k][3] = a.w;
      dst[k][4] = b.x; dst[k][5] = b.y; dst[k][6] = b.z; dst[k][7] = b.w;
    }
  };

  // 8 swizzled LDS base pointers (granule units): ch*160 + oq*8 + (j ^ xv)
  const int xv = (ch << 2) | oq;
  const float4* A[8];
  #pragma unroll
  for (int j = 0; j < 8; ++j)
    A[j] = &wbuf[ch * 160 + oq * 8 + (j ^ xv)];

  // per-thread global w1 base (granule units): ch*160 + oq*8 + 1
  const float4* WgBase = reinterpret_cast<const float4*>(W) + ch * 160 + oq * 8 + 1;

  float vf[5][2][4];
  if constexpr (!UNIFORM) {
    #pragma unroll
    for (int cc = 0; cc < 5; ++cc)
      #pragma unroll
      for (int k = 0; k < 2; ++k) {
        const float4 tv = *reinterpret_cast<const float4*>(
            &vsum[((b0 + k) * C_N + ch * 5 + cc) * O_N + oq * 4]);
        vf[cc][k][0] = tv.x; vf[cc][k][1] = tv.y; vf[cc][k][2] = tv.z; vf[cc][k][3] = tv.w;
      }
  }

  float sacc[5][2][4];
  #pragma unroll
  for (int cc = 0; cc < 5; ++cc)
    #pragma unroll
    for (int k = 0; k < 2; ++k)
      #pragma unroll
      for (int jo = 0; jo < 4; ++jo) sacc[cc][k][jo] = 0.0f;

  float xc[2][8], xn[2][8];
  stage(0, 0);
  xload(r0, xc);
  __syncthreads();

  #pragma unroll 1
  for (int ci = 0; ci < NCH; ++ci) {
    if (ci + 1 < NCH) stage(ci + 1, (ci + 1) & 1);
    const int sb = (ci & 1) * CG;
    #pragma unroll 2
    for (int rr = 0; rr < CHUNK; ++rr) {
      const int rl = ci * CHUNK + rr;
      const int rn = (rl + 1 < RCHB) ? rl + 1 : rl;
      xload(r0 + rn, xn);                 // prefetch next x under compute
      const float4* Wg = WgBase + (size_t)(r0 + rl) * GRAN;
      body<UNIFORM>(A, sb + rr * GRAN, Wg, xc, vf, sacc);
      #pragma unroll
      for (int k = 0; k < 2; ++k)
        #pragma unroll
        for (int i = 0; i < 8; ++i) xc[k][i] = xn[k][i];
    }
    __syncthreads();
  }

  const float scale = UNIFORM ? 0.1f : 1.0f;
  float* pb = part + (size_t)rtile * SEG;
  #pragma unroll
  for (int cc = 0; cc < 5; ++cc)
    #pragma unroll
    for (int k = 0; k < 2; ++k) {
      float4 v;
      v.x = sacc[cc][k][0] * scale; v.y = sacc[cc][k][1] * scale;
      v.z = sacc[cc][k][2] * scale; v.w = sacc[cc][k][3] * scale;
      *reinterpret_cast<float4*>(
          &pb[((b0 + k) * C_N + ch * 5 + cc) * O_N + oq * 4]) = v;
    }
}

// reduce over rtiles + squash over O=16 per (b,c). grid = SEG/64 blocks.
// MODE 0: vsum = v ; MODE 1: vsum += v ; MODE 2: out = v
template<int MODE>
__global__ __launch_bounds__(256) void reduce_squash(
    const float* __restrict__ part, int nrt,
    float* __restrict__ vsum, float* __restrict__ out)
{
  __shared__ float lds[4][64];
  const int tid = threadIdx.x;
  const int l   = tid & 63;
  const int q   = tid >> 6;
  const int j   = blockIdx.x * 64 + l;
  const float* p = part + j;
  float sv = 0.0f;
  #pragma unroll 4
  for (int rt = q; rt < nrt; rt += 4) sv += p[(size_t)rt * SEG];
  lds[q][l] = sv;
  __syncthreads();
  if (q == 0) {
    sv = lds[0][l] + lds[1][l] + lds[2][l] + lds[3][l];
    float sq = sv * sv;
    sq += __shfl_xor(sq, 1);
    sq += __shfl_xor(sq, 2);
    sq += __shfl_xor(sq, 4);
    sq += __shfl_xor(sq, 8);
    const float scale = sq / (1.0f + sq) * rsqrtf(sq + 1e-8f);
    const float v = scale * sv;
    if constexpr (MODE == 0)      vsum[j] = v;
    else if constexpr (MODE == 1) vsum[j] += v;
    else                          out[j] = v;
  }
}

extern "C" void kernel_launch(void* const* d_in, const int* in_sizes, int n_in,
                              void* d_out, int out_size, void* d_ws, size_t ws_size,
                              hipStream_t stream) {
  (void)in_sizes; (void)n_in; (void)out_size; (void)ws_size;
  const float* x = (const float*)d_in[0];
  const float* W = (const float*)d_in[1];
  float* out  = (float*)d_out;   // doubles as vsum; fully rewritten with v2
  float* part = (float*)d_ws;    // RT * SEG floats = 21 MB
  float* xt   = part + (size_t)RT * SEG;   // 18.9 MB (total 40 MB < ws)

  const dim3 blk(256), accGrid(8 * RT), sqGrid(SEG / 64);

  hipLaunchKernelGGL(transpose_x, dim3((B_TOT * R_TOT) / 256), blk, 0, stream, x, xt);

  // iter 0: uniform coefficients (softmax of zeros)
  hipLaunchKernelGGL((acc_kernel<true>),  accGrid, blk, 0, stream, xt, W, out, part);
  hipLaunchKernelGGL((reduce_squash<0>),  sqGrid,  blk, 0, stream, part, RT, out, out);  // vsum = v0
  // iter 1
  hipLaunchKernelGGL((acc_kernel<false>), accGrid, blk, 0, stream, xt, W, out, part);
  hipLaunchKernelGGL((reduce_squash<1>),  sqGrid,  blk, 0, stream, part, RT, out, out);  // vsum = v0+v1
  // iter 2
  hipLaunchKernelGGL((acc_kernel<false>), accGrid, blk, 0, stream, xt, W, out, part);
  hipLaunchKernelGGL((reduce_squash<2>),  sqGrid,  blk, 0, stream, part, RT, out, out);  // out = v2
}

// Round 15
// 134.131 us; speedup vs baseline: 2.3801x; 2.3254x over previous
//
#include <hip/hip_runtime.h>
#include <hip/hip_fp16.h>
#include <math.h>

// Capsule dynamic routing, fused-recompute. fp32 accumulate, f16 data.
// B=512, R=1152, C=10, O=16, I=8.
//   iter0: c_ij = 1/10 uniform  -> s0 = 0.1 * sum_r u_hat
//   iter2: b2 = u.(v0+v1)       -> only running vsum kept
// R14 post-mortem: global w1 loads put ~200cy VMEM latency on the FMA
// critical path (no chunk prefetch covers them) -> acc 65->105us despite
// ideal FETCH. Reverted to R7 schedule.
// R15 = R7 verbatim + f16 W/x: one ds_read_b128 now fetches a FULL
// 8-elem W row (20 reads/iter vs 40 -> LDS floor 29->15us) and
// v_dot2_f32_f16 halves einsum VALU (fp32 accumulation). x converted
// once (RTN) in transpose; W converted during staging. LDS row layout
// p=(cc*4+jo)*8+(ch*4+oq): compute reads conflict-free by construction,
// all offsets compile-time. Accuracy: f16 RTN eps 2^-11 -> absmax ~1e-3
// vs threshold 4.08e-3.

#define R_TOT 1152
#define C_N 10
#define O_N 16
#define I_N 8
#define B_TOT 512
#define RT 64                                   // rtile count (partial slices)
#define RCHB 18                                 // r's per block
#define CHUNK 6                                 // r's per staged chunk
#define NCH 3                                   // chunks per block
#define SEG (B_TOT * C_N * O_N)                 // 81920 floats per partial slice
#define ROWS (C_N * O_N)                        // 160 W rows per r (16B each in f16)
#define CGR (CHUNK * ROWS)                      // 960 rows per chunk

typedef _Float16 h2 __attribute__((ext_vector_type(2)));

// pack two fp32 -> f16x2 (RTN via __float2half)
__device__ __forceinline__ unsigned packf2(float a, float b) {
  unsigned ua = (unsigned)__half_as_ushort(__float2half(a));
  unsigned ub = (unsigned)__half_as_ushort(__float2half(b));
  return ua | (ub << 16);
}

// acc += dot2(w, x) in fp32
__device__ __forceinline__ float dot2acc(unsigned w, unsigned x, float acc) {
#if __has_builtin(__builtin_amdgcn_fdot2)
  return __builtin_amdgcn_fdot2(__builtin_bit_cast(h2, w),
                                __builtin_bit_cast(h2, x), acc, false);
#else
  h2 hw = __builtin_bit_cast(h2, w), hx = __builtin_bit_cast(h2, x);
  return acc + (float)hw[0] * (float)hx[0] + (float)hw[1] * (float)hx[1];
#endif
}

// quad_perm DPP cross-lane adds (VALU pipe, not LDS): xor1 / xor2 over oq.
__device__ __forceinline__ float quad_add1(float v) {
  return v + __int_as_float(__builtin_amdgcn_update_dpp(
      0, __float_as_int(v), 0xB1 /*[1,0,3,2]*/, 0xF, 0xF, true));
}
__device__ __forceinline__ float quad_add2(float v) {
  return v + __int_as_float(__builtin_amdgcn_update_dpp(
      0, __float_as_int(v), 0x4E /*[2,3,0,1]*/, 0xF, 0xF, true));
}

// x[b][r][i] fp32 -> xt[r][b] as 8 packed f16 (one uint4)
__global__ __launch_bounds__(256) void transpose_x(
    const float* __restrict__ x, uint4* __restrict__ xt)
{
  const int t = blockIdx.x * 256 + threadIdx.x;   // t = b*R_TOT + r
  const int b = t / R_TOT;
  const int r = t - b * R_TOT;
  const float4* src = reinterpret_cast<const float4*>(x) + (size_t)t * 2;
  const float4 a = src[0], c = src[1];
  uint4 o;
  o.x = packf2(a.x, a.y); o.y = packf2(a.z, a.w);
  o.z = packf2(c.x, c.y); o.w = packf2(c.z, c.w);
  xt[(size_t)r * B_TOT + b] = o;
}

// one r-step: u = W.x for this thread's (5c x 4o x 2b), then routing update.
// W row (8 f16) = ONE ds_read_b128; 4 chained dot2 per u, fp32 acc.
template<bool UNIFORM>
__device__ __forceinline__ void body(
    const uint4* __restrict__ A16, int slabG,   // row offset (runtime)
    const uint4 (&xc)[2],
    const float (&vf)[5][2][4],
    float (&sacc)[5][2][4])
{
  float u[5][2][4];
  #pragma unroll
  for (int cc = 0; cc < 5; ++cc) {
    #pragma unroll
    for (int jo = 0; jo < 4; ++jo) {
      const uint4 w = A16[slabG + ((cc * 4 + jo) << 3)];
      #pragma unroll
      for (int k = 0; k < 2; ++k) {
        u[cc][k][jo] = dot2acc(w.x, xc[k].x,
                       dot2acc(w.y, xc[k].y,
                       dot2acc(w.z, xc[k].z,
                       dot2acc(w.w, xc[k].w, 0.0f))));
      }
    }
  }

  if constexpr (UNIFORM) {
    #pragma unroll
    for (int cc = 0; cc < 5; ++cc)
      #pragma unroll
      for (int k = 0; k < 2; ++k)
        #pragma unroll
        for (int jo = 0; jo < 4; ++jo)
          sacc[cc][k][jo] += u[cc][k][jo];
  } else {
    float bij[5][2];
    #pragma unroll
    for (int cc = 0; cc < 5; ++cc) {
      #pragma unroll
      for (int k = 0; k < 2; ++k) {
        float a = u[cc][k][0] * vf[cc][k][0] + u[cc][k][1] * vf[cc][k][1]
                + u[cc][k][2] * vf[cc][k][2] + u[cc][k][3] * vf[cc][k][3];
        a = quad_add1(a);        // + lane^1  (oq)
        a = quad_add2(a);        // + lane^2  (oq)
        bij[cc][k] = a;
      }
    }
    #pragma unroll
    for (int k = 0; k < 2; ++k) {
      float m = bij[0][k];
      #pragma unroll
      for (int cc = 1; cc < 5; ++cc) m = fmaxf(m, bij[cc][k]);
      m = fmaxf(m, __shfl_xor(m, 4));
      float e[5];
      float den = 0.0f;
      #pragma unroll
      for (int cc = 0; cc < 5; ++cc) { e[cc] = __expf(bij[cc][k] - m); den += e[cc]; }
      den += __shfl_xor(den, 4);
      const float inv = __builtin_amdgcn_rcpf(den);
      #pragma unroll
      for (int cc = 0; cc < 5; ++cc) {
        const float cw = e[cc] * inv;
        #pragma unroll
        for (int jo = 0; jo < 4; ++jo)
          sacc[cc][k][jo] += cw * u[cc][k][jo];
      }
    }
  }
}

// lane map: oq = lane&3, ch = (lane>>2)&1, bl = lane>>3; thread owns
// b0 = btile*64 + wave*16 + bl*2 (+k), c = ch*5+cc, o = oq*4+jo.
// grid 512 (1D): xcd = bid&7, idx = bid>>3; rtile = xcd*8 + (idx&7),
// btile = idx>>3. Each XCD owns 8 contiguous rtiles.
template<bool UNIFORM>
__global__ __launch_bounds__(256, 2) void acc_kernel(
    const uint4* __restrict__ xt, const float* __restrict__ W,
    const float* __restrict__ vsum, float* __restrict__ part)
{
  __shared__ uint4 wbuf[2 * CGR];   // 30 KB: two 6-slab f16 chunks

  const int tid  = threadIdx.x;
  const int wave = tid >> 6;
  const int lane = tid & 63;
  const int oq   = lane & 3;
  const int ch   = (lane >> 2) & 1;
  const int bl   = lane >> 3;

  const int bid   = blockIdx.x;
  const int xcd   = bid & 7;
  const int idx   = bid >> 3;             // 0..63
  const int rtile = xcd * 8 + (idx & 7);
  const int btile = idx >> 3;             // 0..7

  const int b0 = btile * 64 + wave * 16 + bl * 2;
  const int r0 = rtile * RCHB;

  // stage CHUNK W slabs as f16 rows; row (c,o) -> p=(cc*4+jo)*8+(ch*4+oq)
  auto stage = [&](int ci, int buf) {
    const int rbase = r0 + ci * CHUNK;
    #pragma unroll 1
    for (int g = tid; g < CGR; g += 256) {
      const int s   = g / ROWS;
      const int row = g - s * ROWS;
      const float4* wsrc = reinterpret_cast<const float4*>(W)
                         + ((size_t)(rbase + s) * ROWS + row) * 2;
      const float4 a = wsrc[0], c = wsrc[1];
      const int ci_  = row >> 4, o = row & 15;
      const int chr  = (ci_ >= 5) ? 1 : 0;
      const int ccr  = ci_ - chr * 5;
      const int p    = ((ccr * 4 + (o & 3)) << 3) | (chr * 4 + (o >> 2));
      uint4 v;
      v.x = packf2(a.x, a.y); v.y = packf2(a.z, a.w);
      v.z = packf2(c.x, c.y); v.w = packf2(c.z, c.w);
      wbuf[buf * CGR + s * ROWS + p] = v;
    }
  };

  auto xload = [&](int r, uint4 (&dst)[2]) {
    const uint4* xp = xt + (size_t)r * B_TOT + b0;
    dst[0] = xp[0];
    dst[1] = xp[1];
  };

  // per-thread LDS read base (row units); all (cc,jo) offsets compile-time
  const uint4* A16 = wbuf + (ch * 4 + oq);

  float vf[5][2][4];
  if constexpr (!UNIFORM) {
    #pragma unroll
    for (int cc = 0; cc < 5; ++cc)
      #pragma unroll
      for (int k = 0; k < 2; ++k) {
        const float4 tv = *reinterpret_cast<const float4*>(
            &vsum[((b0 + k) * C_N + ch * 5 + cc) * O_N + oq * 4]);
        vf[cc][k][0] = tv.x; vf[cc][k][1] = tv.y; vf[cc][k][2] = tv.z; vf[cc][k][3] = tv.w;
      }
  }

  float sacc[5][2][4];
  #pragma unroll
  for (int cc = 0; cc < 5; ++cc)
    #pragma unroll
    for (int k = 0; k < 2; ++k)
      #pragma unroll
      for (int jo = 0; jo < 4; ++jo) sacc[cc][k][jo] = 0.0f;

  uint4 xc[2], xn[2];
  stage(0, 0);
  xload(r0, xc);
  __syncthreads();

  #pragma unroll 1
  for (int ci = 0; ci < NCH; ++ci) {
    if (ci + 1 < NCH) stage(ci + 1, (ci + 1) & 1);
    const int sb = (ci & 1) * CGR;
    #pragma unroll 2
    for (int rr = 0; rr < CHUNK; ++rr) {
      const int rl = ci * CHUNK + rr;
      const int rn = (rl + 1 < RCHB) ? rl + 1 : rl;
      xload(r0 + rn, xn);                 // prefetch next x under compute
      body<UNIFORM>(A16, sb + rr * ROWS, xc, vf, sacc);
      xc[0] = xn[0]; xc[1] = xn[1];
    }
    __syncthreads();
  }

  const float scale = UNIFORM ? 0.1f : 1.0f;
  float* pb = part + (size_t)rtile * SEG;
  #pragma unroll
  for (int cc = 0; cc < 5; ++cc)
    #pragma unroll
    for (int k = 0; k < 2; ++k) {
      float4 v;
      v.x = sacc[cc][k][0] * scale; v.y = sacc[cc][k][1] * scale;
      v.z = sacc[cc][k][2] * scale; v.w = sacc[cc][k][3] * scale;
      *reinterpret_cast<float4*>(
          &pb[((b0 + k) * C_N + ch * 5 + cc) * O_N + oq * 4]) = v;
    }
}

// reduce over rtiles + squash over O=16 per (b,c). grid = SEG/64 blocks.
// MODE 0: vsum = v ; MODE 1: vsum += v ; MODE 2: out = v
template<int MODE>
__global__ __launch_bounds__(256) void reduce_squash(
    const float* __restrict__ part, int nrt,
    float* __restrict__ vsum, float* __restrict__ out)
{
  __shared__ float lds[4][64];
  const int tid = threadIdx.x;
  const int l   = tid & 63;
  const int q   = tid >> 6;
  const int j   = blockIdx.x * 64 + l;
  const float* p = part + j;
  float sv = 0.0f;
  #pragma unroll 4
  for (int rt = q; rt < nrt; rt += 4) sv += p[(size_t)rt * SEG];
  lds[q][l] = sv;
  __syncthreads();
  if (q == 0) {
    sv = lds[0][l] + lds[1][l] + lds[2][l] + lds[3][l];
    float sq = sv * sv;
    sq += __shfl_xor(sq, 1);
    sq += __shfl_xor(sq, 2);
    sq += __shfl_xor(sq, 4);
    sq += __shfl_xor(sq, 8);
    const float scale = sq / (1.0f + sq) * rsqrtf(sq + 1e-8f);
    const float v = scale * sv;
    if constexpr (MODE == 0)      vsum[j] = v;
    else if constexpr (MODE == 1) vsum[j] += v;
    else                          out[j] = v;
  }
}

extern "C" void kernel_launch(void* const* d_in, const int* in_sizes, int n_in,
                              void* d_out, int out_size, void* d_ws, size_t ws_size,
                              hipStream_t stream) {
  (void)in_sizes; (void)n_in; (void)out_size; (void)ws_size;
  const float* x = (const float*)d_in[0];
  const float* W = (const float*)d_in[1];
  float* out  = (float*)d_out;   // doubles as vsum; fully rewritten with v2
  float* part = (float*)d_ws;    // RT * SEG floats = 21 MB
  uint4* xt   = reinterpret_cast<uint4*>(part + (size_t)RT * SEG);  // 9.4 MB f16

  const dim3 blk(256), accGrid(8 * RT), sqGrid(SEG / 64);

  hipLaunchKernelGGL(transpose_x, dim3((B_TOT * R_TOT) / 256), blk, 0, stream, x, xt);

  // iter 0: uniform coefficients (softmax of zeros)
  hipLaunchKernelGGL((acc_kernel<true>),  accGrid, blk, 0, stream, xt, W, out, part);
  hipLaunchKernelGGL((reduce_squash<0>),  sqGrid,  blk, 0, stream, part, RT, out, out);  // vsum = v0
  // iter 1
  hipLaunchKernelGGL((acc_kernel<false>), accGrid, blk, 0, stream, xt, W, out, part);
  hipLaunchKernelGGL((reduce_squash<1>),  sqGrid,  blk, 0, stream, part, RT, out, out);  // vsum = v0+v1
  // iter 2
  hipLaunchKernelGGL((acc_kernel<false>), accGrid, blk, 0, stream, xt, W, out, part);
  hipLaunchKernelGGL((reduce_squash<2>),  sqGrid,  blk, 0, stream, part, RT, out, out);  // out = v2
}